// Round 6
// baseline (16725.305 us; speedup 1.0000x reference)
//
#include <hip/hip_runtime.h>

typedef unsigned short u16;
typedef unsigned int u32;
typedef __bf16 bf16x8 __attribute__((ext_vector_type(8)));
typedef float f32x4 __attribute__((ext_vector_type(4)));

#define D_    768
#define DM_   3072
#define NL_   12
#define NT_   577
#define NP_   576
#define B_    64
#define MREAL (B_*NT_)      /* 36928 */
#define MPAD2 37120         /* 290*128 */
#define NC_   1000
#define IMG_  384

__device__ __forceinline__ float bf2f(u16 v){
  union { unsigned u; float f; } c; c.u = ((unsigned)v) << 16; return c.f;
}
__device__ __forceinline__ u16 f2bf(float f){
  union { float f; unsigned u; } c; c.f = f;
  unsigned r = c.u + 0x7FFFu + ((c.u >> 16) & 1u);
  return (u16)(r >> 16);
}
__device__ __forceinline__ float gelu_f(float x){
  return 0.5f * x * (1.0f + erff(x * 0.70710678118654752f));
}
__device__ __forceinline__ void gload16(const void* g, void* l){
  __builtin_amdgcn_global_load_lds((const __attribute__((address_space(1))) void*)g,
                                   (__attribute__((address_space(3))) void*)l, 16, 0, 0);
}

#define SB_ __builtin_amdgcn_sched_barrier(0)

// ---------------------------------------------------------------------------
// B-in-LDS GEMM: C[M,N] = A[M,K] bf16 row-major x Bt[N,K] bf16 (B^T).
// 128x128 tile, BK=64, 4 waves (2Mx2N, 64x64 each). A-fragments loaded
// DIRECTLY global->VGPR (no LDS staging); only B staged in LDS (dbuf 32KiB
// -> ~3 blocks/CU). Counted vmcnt(4): per iter issue A(t) 8xb128, stage
// B(t+1) 4xgload16, vmcnt(4) retires B(t)+A(t) and keeps the stage flying.
// Proven XOR swizzle on B (source col8 ^= row&7; read byte ^= (lrow&7)<<4).
// EPI: 0=bf16 bias, 1=f32 bias+res, 2=bf16 gelu(bias), 3=f32 gelu(bias)+res,
//      4=f32 bias, 5=f32 gelu(bias) bounded store [Ms,Ns]
// ---------------------------------------------------------------------------
template<int EPI>
__global__ __launch_bounds__(256) void gemmB_k(
    const u16* __restrict__ A, const u16* __restrict__ Bt,
    const float* __restrict__ bias, const float* __restrict__ res,
    void* __restrict__ outv, int K, int ldo, int nbn, int Ms, int Ns)
{
  __shared__ u16 Bs[2][128*64];
  const int tid = threadIdx.x;
  const int l   = tid & 63;
  const int wid = tid >> 6;
  const int wm  = wid >> 1, wn = wid & 1;
  const int lrow = l & 15;
  const int g8   = (l >> 4) * 8;

  // bijective XCD swizzle (m204), bn-fastest
  const int nwg = gridDim.x;
  const int q = nwg >> 3, r = nwg & 7;
  const int xcd = blockIdx.x & 7, o = blockIdx.x >> 3;
  const int wg = (xcd < r ? xcd * (q + 1) : r * (q + 1) + (xcd - r) * q) + o;
  const int bm = wg / nbn, bn = wg % nbn;

  // B staging: chunk i covers rows 32i..32i+31; dest linear = tid*8 + i*2048
  const int cs8 = ((tid & 7) ^ ((tid >> 3) & 7)) * 8;
  const u16* bP[4];
  #pragma unroll
  for (int i = 0; i < 4; i++)
    bP[i] = Bt + (size_t)(bn*128 + (tid >> 3) + 32*i) * K + cs8;

  // A row pointers (per-lane, direct global fragment loads)
  const u16* aP[4];
  #pragma unroll
  for (int mi = 0; mi < 4; mi++)
    aP[mi] = A + (size_t)(bm*128 + wm*64 + mi*16 + lrow) * K + g8;

  f32x4 acc[4][4];
  #pragma unroll
  for (int i = 0; i < 4; i++)
    #pragma unroll
    for (int j = 0; j < 4; j++) acc[i][j] = {0.f, 0.f, 0.f, 0.f};

  const int nk = K >> 6;
  // prologue: stage B(0) -> buf 0
  #pragma unroll
  for (int i = 0; i < 4; i++) {
    gload16(bP[i], &Bs[0][tid*8 + i*2048]);
    bP[i] += 64;
  }

  const int sw   = (lrow & 7) << 4;
  const int colA = (l >> 4) << 4;

  for (int t = 0; t < nk; ++t) {
    const int cur = t & 1;
    const bool pre = (t + 1 < nk);

    // A-fragments for tile t: 8 x b128 global->VGPR
    bf16x8 ga0[4], ga1[4];
    #pragma unroll
    for (int mi = 0; mi < 4; mi++) ga0[mi] = *(const bf16x8*)(aP[mi]);
    #pragma unroll
    for (int mi = 0; mi < 4; mi++) ga1[mi] = *(const bf16x8*)(aP[mi] + 32);
    #pragma unroll
    for (int mi = 0; mi < 4; mi++) aP[mi] += 64;

    // stage B(t+1) -> buf cur^1 (stays in flight across the vmcnt)
    if (pre) {
      #pragma unroll
      for (int i = 0; i < 4; i++) {
        gload16(bP[i], &Bs[cur^1][tid*8 + i*2048]);
        bP[i] += 64;
      }
    }
    SB_;
    if (pre) asm volatile("s_waitcnt vmcnt(4)" ::: "memory");
    else     asm volatile("s_waitcnt vmcnt(0)" ::: "memory");
    SB_;
    __builtin_amdgcn_s_barrier();
    SB_;

    const char* Bb = (const char*)&Bs[cur][0];
    bf16x8 bfr[4];
    // kk = 0
    #pragma unroll
    for (int ni = 0; ni < 4; ni++)
      bfr[ni] = *(const bf16x8*)(Bb + ((wn*64 + ni*16 + lrow) << 7) + (colA ^ sw));
    asm volatile("s_waitcnt lgkmcnt(0)" ::: "memory");
    SB_;
    __builtin_amdgcn_s_setprio(1);
    #pragma unroll
    for (int mi = 0; mi < 4; mi++)
      #pragma unroll
      for (int ni = 0; ni < 4; ni++)
        acc[mi][ni] = __builtin_amdgcn_mfma_f32_16x16x32_bf16(ga0[mi], bfr[ni], acc[mi][ni], 0, 0, 0);
    __builtin_amdgcn_s_setprio(0);
    SB_;
    // kk = 1
    #pragma unroll
    for (int ni = 0; ni < 4; ni++)
      bfr[ni] = *(const bf16x8*)(Bb + ((wn*64 + ni*16 + lrow) << 7) + ((64 | colA) ^ sw));
    asm volatile("s_waitcnt lgkmcnt(0)" ::: "memory");
    SB_;
    __builtin_amdgcn_s_setprio(1);
    #pragma unroll
    for (int mi = 0; mi < 4; mi++)
      #pragma unroll
      for (int ni = 0; ni < 4; ni++)
        acc[mi][ni] = __builtin_amdgcn_mfma_f32_16x16x32_bf16(ga1[mi], bfr[ni], acc[mi][ni], 0, 0, 0);
    __builtin_amdgcn_s_setprio(0);
    SB_;
    __builtin_amdgcn_s_barrier();   // protect Bs[cur] before t+1 restages it
    SB_;
  }

  const int orow0 = bm*128 + wm*64;
  const int ocol0 = bn*128 + wn*64;
  #pragma unroll
  for (int mi = 0; mi < 4; mi++) {
    #pragma unroll
    for (int ni = 0; ni < 4; ni++) {
      const int col = ocol0 + ni*16 + (l & 15);
      float bv;
      if constexpr (EPI == 5) bv = (col < Ns) ? bias[col] : 0.f;
      else bv = bias[col];
      #pragma unroll
      for (int r2 = 0; r2 < 4; r2++) {
        const int row = orow0 + mi*16 + (l >> 4)*4 + r2;
        const float v = acc[mi][ni][r2] + bv;
        const size_t idx = (size_t)row * ldo + col;
        if constexpr (EPI == 0) ((u16*)outv)[idx] = f2bf(v);
        else if constexpr (EPI == 1) ((float*)outv)[idx] = v + res[idx];
        else if constexpr (EPI == 2) ((u16*)outv)[idx] = f2bf(gelu_f(v));
        else if constexpr (EPI == 3) ((float*)outv)[idx] = gelu_f(v) + res[idx];
        else if constexpr (EPI == 4) ((float*)outv)[idx] = v;
        else if constexpr (EPI == 5) {
          if (row < Ms && col < Ns) ((float*)outv)[(size_t)row * Ns + col] = gelu_f(v);
        }
      }
    }
  }
}

// ---------------------------------------------------------------------------
__global__ void wconv_k(const float* __restrict__ W, u16* __restrict__ Wt,
                        int K, int N)
{
  __shared__ float tile[32][33];
  const int n0 = blockIdx.x * 32, k0 = blockIdx.y * 32;
  const int tx = threadIdx.x, ty = threadIdx.y;
  #pragma unroll
  for (int r = 0; r < 4; r++) {
    const int kk = k0 + ty + r*8;
    const int nn = n0 + tx;
    tile[ty + r*8][tx] = (nn < N) ? W[(size_t)kk * N + nn] : 0.f;
  }
  __syncthreads();
  #pragma unroll
  for (int r = 0; r < 4; r++) {
    const int nn = n0 + ty + r*8;
    Wt[(size_t)nn * K + k0 + tx] = f2bf(tile[tx][ty + r*8]);
  }
}

// ---------------------------------------------------------------------------
__global__ void patchify_k(const float* __restrict__ x, u16* __restrict__ hb)
{
  const int blk = blockIdx.x;
  const int b = blk / NP_, p = blk % NP_;
  const int pr = p / 24, pc = p % 24;
  const size_t row = (size_t)b * NT_ + 1 + p;
  #pragma unroll
  for (int u = 0; u < 3; u++) {
    const int j  = threadIdx.x + u * 256;
    const int c  = j >> 8, ph = (j >> 4) & 15, pw = j & 15;
    const float v = x[((size_t)(b*3 + c) * IMG_ + pr*16 + ph) * IMG_ + pc*16 + pw];
    hb[row * D_ + j] = f2bf(v);
  }
}

__global__ void posecls_k(float* __restrict__ z, const float* __restrict__ ce,
                          const float* __restrict__ pe)
{
  const int row = blockIdx.x;
  const int t = row % NT_;
  const size_t base = (size_t)row * D_;
  #pragma unroll
  for (int u = 0; u < 3; u++) {
    const int j = threadIdx.x + u * 256;
    if (t == 0) z[base + j] = ce[j] + pe[j];
    else        z[base + j] += pe[(size_t)t * D_ + j];
  }
}

// LayerNorm: one wave per row, float4 loads, f32 in -> bf16 out
__global__ void ln_k(const float* __restrict__ z, const float* __restrict__ w,
                     const float* __restrict__ b, u16* __restrict__ out)
{
  const int row = blockIdx.x * 4 + (threadIdx.x >> 6);
  const int l = threadIdx.x & 63;
  const float4* zr = (const float4*)(z + (size_t)row * D_);
  float4 xq[3];
  float s = 0.f;
  #pragma unroll
  for (int j = 0; j < 3; j++) {
    xq[j] = zr[j*64 + l];
    s += xq[j].x + xq[j].y + xq[j].z + xq[j].w;
  }
  #pragma unroll
  for (int m = 1; m < 64; m <<= 1) s += __shfl_xor(s, m, 64);
  const float mean = s * (1.0f / 768.0f);
  float ss = 0.f;
  #pragma unroll
  for (int j = 0; j < 3; j++) {
    const float dx = xq[j].x-mean, dy = xq[j].y-mean, dz = xq[j].z-mean, dw = xq[j].w-mean;
    ss += dx*dx + dy*dy + dz*dz + dw*dw;
  }
  #pragma unroll
  for (int m = 1; m < 64; m <<= 1) ss += __shfl_xor(ss, m, 64);
  const float rinv = rsqrtf(ss * (1.0f / 768.0f) + 1e-5f);
  const size_t ob = (size_t)row * D_;
  #pragma unroll
  for (int j = 0; j < 3; j++) {
    const int c = (j*64 + l) * 4;
    const float4 wv = *(const float4*)(w + c);
    const float4 bv = *(const float4*)(b + c);
    ushort4 ov;
    ov.x = f2bf((xq[j].x - mean) * rinv * wv.x + bv.x);
    ov.y = f2bf((xq[j].y - mean) * rinv * wv.y + bv.y);
    ov.z = f2bf((xq[j].z - mean) * rinv * wv.z + bv.z);
    ov.w = f2bf((xq[j].w - mean) * rinv * wv.w + bv.w);
    *(ushort4*)(out + ob + c) = ov;
  }
}

// Final LN over cls rows -> yb[128][768] bf16 (rows >= 64 zeroed)
__global__ void lncls_k(const float* __restrict__ z, const float* __restrict__ w,
                        const float* __restrict__ b, u16* __restrict__ out)
{
  const int row = blockIdx.x * 4 + (threadIdx.x >> 6);   // 0..127
  const int l = threadIdx.x & 63;
  const size_t ob = (size_t)row * D_;
  if (row >= B_) {
    #pragma unroll
    for (int j = 0; j < 12; j++) out[ob + j*64 + l] = 0;
    return;
  }
  const float* zr = z + (size_t)row * NT_ * D_;
  float xv[12];
  float s = 0.f;
  #pragma unroll
  for (int j = 0; j < 12; j++) { xv[j] = zr[j*64 + l]; s += xv[j]; }
  #pragma unroll
  for (int m = 1; m < 64; m <<= 1) s += __shfl_xor(s, m, 64);
  const float mean = s * (1.0f / 768.0f);
  float ss = 0.f;
  #pragma unroll
  for (int j = 0; j < 12; j++) { const float d = xv[j] - mean; ss += d * d; }
  #pragma unroll
  for (int m = 1; m < 64; m <<= 1) ss += __shfl_xor(ss, m, 64);
  const float rinv = rsqrtf(ss * (1.0f / 768.0f) + 1e-5f);
  #pragma unroll
  for (int j = 0; j < 12; j++) {
    const int cidx = j*64 + l;
    out[ob + cidx] = f2bf((xv[j] - mean) * rinv * w[cidx] + b[cidx]);
  }
}

// ---------------------------------------------------------------------------
// MFMA per-token head-axis attention (round-3 proven).
// ---------------------------------------------------------------------------
__global__ __launch_bounds__(256) void attn_k(const u16* __restrict__ qkv,
                                              u16* __restrict__ o)
{
  const int tok = (blockIdx.x * 256 + threadIdx.x) >> 6;
  const int l  = threadIdx.x & 63;
  const int g  = l >> 4, li = l & 15;
  const size_t rb = (size_t)tok * (3 * D_);

  f32x4 s = {0.f, 0.f, 0.f, 0.f};
  #pragma unroll
  for (int kt = 0; kt < 2; kt++) {
    const bf16x8 ka = *(const bf16x8*)(qkv + rb + D_ + li*64 + g*8 + kt*32);
    const bf16x8 qb = *(const bf16x8*)(qkv + rb +      li*64 + g*8 + kt*32);
    s = __builtin_amdgcn_mfma_f32_16x16x32_bf16(ka, qb, s, 0, 0, 0);
  }

  float sv[4];
  #pragma unroll
  for (int r2 = 0; r2 < 4; r2++) sv[r2] = s[r2] * 0.125f;
  float mx = (g < 3) ? fmaxf(fmaxf(sv[0], sv[1]), fmaxf(sv[2], sv[3])) : -1e30f;
  mx = fmaxf(mx, __shfl_xor(mx, 16, 64));
  mx = fmaxf(mx, __shfl_xor(mx, 32, 64));
  float p[4], den = 0.f;
  #pragma unroll
  for (int r2 = 0; r2 < 4; r2++) {
    p[r2] = (g < 3) ? __expf(sv[r2] - mx) : 0.f;
    den += p[r2];
  }
  den += __shfl_xor(den, 16, 64);
  den += __shfl_xor(den, 32, 64);
  const float rden = 1.0f / den;
  #pragma unroll
  for (int r2 = 0; r2 < 4; r2++) p[r2] *= rden;

  const u32 pk01 = ((u32)f2bf(p[1]) << 16) | f2bf(p[0]);
  const u32 pk23 = ((u32)f2bf(p[3]) << 16) | f2bf(p[2]);

  const int srcA = (li + (g << 5)) & 63;
  const int srcB = (srcA + 16) & 63;
  u32 b0 = (u32)__shfl((int)pk01, srcA, 64);
  u32 b1 = (u32)__shfl((int)pk23, srcA, 64);
  u32 b2 = (u32)__shfl((int)pk01, srcB, 64);
  u32 b3 = (u32)__shfl((int)pk23, srcB, 64);
  if (g >= 2) { b0 = 0; b1 = 0; b2 = 0; b3 = 0; }
  union { u32 u[4]; bf16x8 v; } pb;
  pb.u[0] = b0; pb.u[1] = b1; pb.u[2] = b2; pb.u[3] = b3;

  const size_t ob = (size_t)tok * D_;
  #pragma unroll
  for (int t = 0; t < 4; t++) {
    union { u16 a[8]; bf16x8 v; } va;
    #pragma unroll
    for (int jp = 0; jp < 8; jp++) {
      const int j = g * 8 + jp;
      va.a[jp] = (j < 12) ? qkv[rb + 2*D_ + j*64 + t*16 + li] : (u16)0;
    }
    f32x4 oac = {0.f, 0.f, 0.f, 0.f};
    oac = __builtin_amdgcn_mfma_f32_16x16x32_bf16(va.v, pb.v, oac, 0, 0, 0);
    if (li < 12) {
      ushort4 ov;
      ov.x = f2bf(oac[0]); ov.y = f2bf(oac[1]);
      ov.z = f2bf(oac[2]); ov.w = f2bf(oac[3]);
      *(ushort4*)(o + ob + li*64 + t*16 + g*4) = ov;
    }
  }
}

// ---------------------------------------------------------------------------
extern "C" void kernel_launch(void* const* d_in, const int* in_sizes, int n_in,
                              void* d_out, int out_size, void* d_ws, size_t ws_size,
                              hipStream_t stream)
{
  const float* x    = (const float*)d_in[0];
  const float* ce   = (const float*)d_in[1];
  const float* pe   = (const float*)d_in[2];
  const float* pw   = (const float*)d_in[3];
  const float* pb   = (const float*)d_in[4];
  const float* qkvw = (const float*)d_in[5];
  const float* qkvb = (const float*)d_in[6];
  const float* topw = (const float*)d_in[7];
  const float* topb = (const float*)d_in[8];
  const float* l1w  = (const float*)d_in[9];
  const float* l1b  = (const float*)d_in[10];
  const float* l2w  = (const float*)d_in[11];
  const float* l2b  = (const float*)d_in[12];
  const float* w1   = (const float*)d_in[13];
  const float* b1   = (const float*)d_in[14];
  const float* w2   = (const float*)d_in[15];
  const float* b2   = (const float*)d_in[16];
  const float* l3w  = (const float*)d_in[17];
  const float* l3b  = (const float*)d_in[18];
  const float* hw1  = (const float*)d_in[19];
  const float* hb1  = (const float*)d_in[20];
  const float* hw2  = (const float*)d_in[21];
  const float* hb2  = (const float*)d_in[22];

  char* ws = (char*)d_ws;
  constexpr size_t SZ_Z  = (size_t)MPAD2 * D_ * 4;
  constexpr size_t SZ_HB = (size_t)MPAD2 * D_ * 2;
  constexpr size_t SZ_QM = (size_t)MPAD2 * DM_ * 2;
  constexpr size_t SZ_WB = (size_t)DM_ * 1024 * 2;
  constexpr size_t SZ_YB = (size_t)128 * D_ * 2;
  float* z  = (float*)ws;
  u16*   hb = (u16*)(ws + SZ_Z);
  u16*   qm = (u16*)(ws + SZ_Z + SZ_HB);
  u16*   wb = (u16*)(ws + SZ_Z + SZ_HB + SZ_QM);
  u16*   yb = (u16*)(ws + SZ_Z + SZ_HB + SZ_QM + SZ_WB);
  u16*   t1 = (u16*)(ws + SZ_Z + SZ_HB + SZ_QM + SZ_WB + SZ_YB);

  const dim3 blk(256);
  const dim3 wblk(32, 8);
  const int MT = MPAD2 / 128;   // 290

  // Patch embedding
  patchify_k<<<B_ * NP_, blk, 0, stream>>>(x, hb);
  wconv_k<<<dim3(D_/32, D_/32), wblk, 0, stream>>>(pw, wb, D_, D_);
  gemmB_k<4><<<6*MT, blk, 0, stream>>>(hb, wb, pb, nullptr, z, D_, D_, 6, 0, 0);
  posecls_k<<<MREAL, blk, 0, stream>>>(z, ce, pe);

  for (int i = 0; i < NL_; i++) {
    ln_k<<<MPAD2/4, blk, 0, stream>>>(z, l1w + i*D_, l1b + i*D_, hb);
    wconv_k<<<dim3(3*D_/32, D_/32), wblk, 0, stream>>>(qkvw + (size_t)i*D_*3*D_, wb, D_, 3*D_);
    gemmB_k<0><<<18*MT, blk, 0, stream>>>(hb, wb, qkvb + i*3*D_, nullptr, qm, D_, 3*D_, 18, 0, 0);
    attn_k<<<MREAL/4, blk, 0, stream>>>(qm, hb);
    wconv_k<<<dim3(D_/32, D_/32), wblk, 0, stream>>>(topw + (size_t)i*D_*D_, wb, D_, D_);
    gemmB_k<1><<<6*MT, blk, 0, stream>>>(hb, wb, topb + i*D_, z, z, D_, D_, 6, 0, 0);
    ln_k<<<MPAD2/4, blk, 0, stream>>>(z, l2w + i*D_, l2b + i*D_, hb);
    wconv_k<<<dim3(DM_/32, D_/32), wblk, 0, stream>>>(w1 + (size_t)i*D_*DM_, wb, D_, DM_);
    gemmB_k<2><<<24*MT, blk, 0, stream>>>(hb, wb, b1 + i*DM_, nullptr, qm, D_, DM_, 24, 0, 0);
    wconv_k<<<dim3(D_/32, DM_/32), wblk, 0, stream>>>(w2 + (size_t)i*DM_*D_, wb, DM_, D_);
    gemmB_k<3><<<6*MT, blk, 0, stream>>>(qm, wb, b2 + i*D_, z, z, DM_, D_, 6, 0, 0);
  }

  // Head: LN(cls) -> MLP with gelu after both linears
  lncls_k<<<32, blk, 0, stream>>>(z, l3w, l3b, yb);
  wconv_k<<<dim3(DM_/32, D_/32), wblk, 0, stream>>>(hw1, wb, D_, DM_);
  gemmB_k<2><<<24, blk, 0, stream>>>(yb, wb, hb1, nullptr, t1, D_, DM_, 24, 0, 0);
  wconv_k<<<dim3(1024/32, DM_/32), wblk, 0, stream>>>(hw2, wb, DM_, NC_);
  gemmB_k<5><<<8, blk, 0, stream>>>(t1, wb, hb2, nullptr, (float*)d_out, DM_, 1024, 8, B_, NC_);
}

// Round 7
// 11605.683 us; speedup vs baseline: 1.4411x; 1.4411x over previous
//
#include <hip/hip_runtime.h>

typedef unsigned short u16;
typedef unsigned int u32;
typedef __bf16 bf16x8 __attribute__((ext_vector_type(8)));
typedef float f32x4 __attribute__((ext_vector_type(4)));

#define D_    768
#define DM_   3072
#define NL_   12
#define NT_   577
#define NP_   576
#define B_    64
#define MREAL (B_*NT_)      /* 36928 */
#define MPAD2 37120         /* 145*256 = 290*128 */
#define NC_   1000
#define IMG_  384

__device__ __forceinline__ float bf2f(u16 v){
  union { unsigned u; float f; } c; c.u = ((unsigned)v) << 16; return c.f;
}
__device__ __forceinline__ u16 f2bf(float f){
  union { float f; unsigned u; } c; c.f = f;
  unsigned r = c.u + 0x7FFFu + ((c.u >> 16) & 1u);
  return (u16)(r >> 16);
}
__device__ __forceinline__ float gelu_f(float x){
  return 0.5f * x * (1.0f + erff(x * 0.70710678118654752f));
}
__device__ __forceinline__ void gload16(const void* g, void* l){
  __builtin_amdgcn_global_load_lds((const __attribute__((address_space(1))) void*)g,
                                   (__attribute__((address_space(3))) void*)l, 16, 0, 0);
}
// barrier with compiler-level memory ordering but NO waitcnt drain
#define BAR_ asm volatile("s_barrier" ::: "memory")

__device__ __forceinline__ void epi_store(int EPI, void* outv, const float* res,
                                          size_t idx, float v){
  // helper not used; epilogues inline below
}

// ---------------------------------------------------------------------------
// 256x256 dbuf GEMM, BK=64, 8 waves (2Mx4N), counted vmcnt(8), free-run body
// (no sched_barrier pinning, no manual lgkmcnt — compiler schedules reads/MFMA).
// EPI: 0=bf16 bias, 2=bf16 gelu(bias)
// ---------------------------------------------------------------------------
template<int EPI>
__global__ __launch_bounds__(512, 1) void gemm256_k(
    const u16* __restrict__ A, const u16* __restrict__ Bt,
    const float* __restrict__ bias,
    void* __restrict__ outv, int K, int ldo, int nbn)
{
  __shared__ u16 lds[2][2][256*64];
  const int tid = threadIdx.x;
  const int l   = tid & 63;
  const int wid = tid >> 6;
  const int wm  = wid >> 2, wn = wid & 3;
  const int lrow = l & 15;

  const int nwg = gridDim.x;
  const int q = nwg >> 3, r = nwg & 7;
  const int xcd = blockIdx.x & 7, o = blockIdx.x >> 3;
  const int wg = (xcd < r ? xcd * (q + 1) : r * (q + 1) + (xcd - r) * q) + o;
  const int bm = wg / nbn, bn = wg % nbn;

  const int cs8 = ((tid & 7) ^ ((tid >> 3) & 7)) * 8;
  const int rb  = tid >> 3;                       // 0..63
  const u16* aP[4]; const u16* bP[4];
  #pragma unroll
  for (int i = 0; i < 4; i++) {
    aP[i] = A  + (size_t)(bm*256 + rb + 64*i) * K + cs8;
    bP[i] = Bt + (size_t)(bn*256 + rb + 64*i) * K + cs8;
  }
  const int ldst = tid * 8;

  f32x4 acc[8][4];
  #pragma unroll
  for (int i = 0; i < 8; i++)
    #pragma unroll
    for (int j = 0; j < 4; j++) acc[i][j] = {0.f, 0.f, 0.f, 0.f};

  const int nk = K >> 6;
  #pragma unroll
  for (int i = 0; i < 4; i++) {
    gload16(aP[i], &lds[0][0][ldst + i*4096]);
    gload16(bP[i], &lds[0][1][ldst + i*4096]);
    aP[i] += 64; bP[i] += 64;
  }

  const int sw  = (lrow & 7) << 4;
  const int g16 = (l >> 4) << 4;

  for (int t = 0; t < nk; ++t) {
    const int cur = t & 1;
    if (t + 1 < nk) {
      #pragma unroll
      for (int i = 0; i < 4; i++) {
        gload16(aP[i], &lds[cur^1][0][ldst + i*4096]);
        gload16(bP[i], &lds[cur^1][1][ldst + i*4096]);
        aP[i] += 64; bP[i] += 64;
      }
      asm volatile("s_waitcnt vmcnt(8)" ::: "memory");
    } else {
      asm volatile("s_waitcnt vmcnt(0)" ::: "memory");
    }
    BAR_;
    const char* As_ = (const char*)&lds[cur][0][0];
    const char* Bs_ = (const char*)&lds[cur][1][0];
    __builtin_amdgcn_s_setprio(1);
    #pragma unroll
    for (int kk = 0; kk < 2; kk++) {
      bf16x8 af[8], bfr[4];
      const int kb = (kk << 6) | g16;
      #pragma unroll
      for (int mi = 0; mi < 8; mi++)
        af[mi] = *(const bf16x8*)(As_ + ((wm*128 + mi*16 + lrow) << 7) + (kb ^ sw));
      #pragma unroll
      for (int ni = 0; ni < 4; ni++)
        bfr[ni] = *(const bf16x8*)(Bs_ + ((wn*64 + ni*16 + lrow) << 7) + (kb ^ sw));
      #pragma unroll
      for (int mi = 0; mi < 8; mi++)
        #pragma unroll
        for (int ni = 0; ni < 4; ni++)
          acc[mi][ni] = __builtin_amdgcn_mfma_f32_16x16x32_bf16(af[mi], bfr[ni], acc[mi][ni], 0, 0, 0);
    }
    __builtin_amdgcn_s_setprio(0);
    BAR_;
  }

  const int orow0 = bm*256 + wm*128;
  const int ocol0 = bn*256 + wn*64;
  #pragma unroll
  for (int mi = 0; mi < 8; mi++) {
    #pragma unroll
    for (int ni = 0; ni < 4; ni++) {
      const int col = ocol0 + ni*16 + (l & 15);
      const float bv = bias[col];
      #pragma unroll
      for (int r2 = 0; r2 < 4; r2++) {
        const int row = orow0 + mi*16 + (l >> 4)*4 + r2;
        const float v = acc[mi][ni][r2] + bv;
        const size_t idx = (size_t)row * ldo + col;
        if constexpr (EPI == 0) ((u16*)outv)[idx] = f2bf(v);
        else if constexpr (EPI == 2) ((u16*)outv)[idx] = f2bf(gelu_f(v));
      }
    }
  }
}

// ---------------------------------------------------------------------------
// 128x128 dbuf GEMM, BK=64, 4 waves (2x2), counted vmcnt(8), 64 KiB LDS
// -> 2 blocks/CU for cross-block overlap. Free-run body.
// EPI: 1=f32 bias+res, 3=f32 gelu(bias)+res, 4=f32 bias
// ---------------------------------------------------------------------------
template<int EPI>
__global__ __launch_bounds__(256, 2) void gemm128_k(
    const u16* __restrict__ A, const u16* __restrict__ Bt,
    const float* __restrict__ bias, const float* __restrict__ res,
    void* __restrict__ outv, int K, int ldo, int nbn)
{
  __shared__ u16 lds[2][2][128*64];   // 64 KiB
  const int tid = threadIdx.x;
  const int l   = tid & 63;
  const int w   = tid >> 6;
  const int wm  = w >> 1, wn = w & 1;
  const int lrow = l & 15;

  const int nwg = gridDim.x;
  const int q = nwg >> 3, r = nwg & 7;
  const int xcd = blockIdx.x & 7, o = blockIdx.x >> 3;
  const int wg = (xcd < r ? xcd * (q + 1) : r * (q + 1) + (xcd - r) * q) + o;
  const int bm = wg / nbn, bn = wg % nbn;

  const int cs8 = ((tid & 7) ^ ((tid >> 3) & 7)) * 8;
  const int rb  = tid >> 3;                       // 0..31
  const u16* aP[4]; const u16* bP[4];
  #pragma unroll
  for (int i = 0; i < 4; i++) {
    aP[i] = A  + (size_t)(bm*128 + rb + 32*i) * K + cs8;
    bP[i] = Bt + (size_t)(bn*128 + rb + 32*i) * K + cs8;
  }
  const int ldst = tid * 8;

  f32x4 acc[4][4];
  #pragma unroll
  for (int i = 0; i < 4; i++)
    #pragma unroll
    for (int j = 0; j < 4; j++) acc[i][j] = {0.f, 0.f, 0.f, 0.f};

  const int nk = K >> 6;
  #pragma unroll
  for (int i = 0; i < 4; i++) {
    gload16(aP[i], &lds[0][0][ldst + i*2048]);
    gload16(bP[i], &lds[0][1][ldst + i*2048]);
    aP[i] += 64; bP[i] += 64;
  }

  const int sw  = (lrow & 7) << 4;
  const int g16 = (l >> 4) << 4;

  for (int t = 0; t < nk; ++t) {
    const int cur = t & 1;
    if (t + 1 < nk) {
      #pragma unroll
      for (int i = 0; i < 4; i++) {
        gload16(aP[i], &lds[cur^1][0][ldst + i*2048]);
        gload16(bP[i], &lds[cur^1][1][ldst + i*2048]);
        aP[i] += 64; bP[i] += 64;
      }
      asm volatile("s_waitcnt vmcnt(8)" ::: "memory");
    } else {
      asm volatile("s_waitcnt vmcnt(0)" ::: "memory");
    }
    BAR_;
    const char* As_ = (const char*)&lds[cur][0][0];
    const char* Bs_ = (const char*)&lds[cur][1][0];
    __builtin_amdgcn_s_setprio(1);
    #pragma unroll
    for (int kk = 0; kk < 2; kk++) {
      bf16x8 af[4], bfr[4];
      const int kb = (kk << 6) | g16;
      #pragma unroll
      for (int mi = 0; mi < 4; mi++)
        af[mi] = *(const bf16x8*)(As_ + ((wm*64 + mi*16 + lrow) << 7) + (kb ^ sw));
      #pragma unroll
      for (int ni = 0; ni < 4; ni++)
        bfr[ni] = *(const bf16x8*)(Bs_ + ((wn*64 + ni*16 + lrow) << 7) + (kb ^ sw));
      #pragma unroll
      for (int mi = 0; mi < 4; mi++)
        #pragma unroll
        for (int ni = 0; ni < 4; ni++)
          acc[mi][ni] = __builtin_amdgcn_mfma_f32_16x16x32_bf16(af[mi], bfr[ni], acc[mi][ni], 0, 0, 0);
    }
    __builtin_amdgcn_s_setprio(0);
    BAR_;
  }

  const int orow0 = bm*128 + wm*64;
  const int ocol0 = bn*128 + wn*64;
  #pragma unroll
  for (int mi = 0; mi < 4; mi++) {
    #pragma unroll
    for (int ni = 0; ni < 4; ni++) {
      const int col = ocol0 + ni*16 + (l & 15);
      const float bv = bias[col];
      #pragma unroll
      for (int r2 = 0; r2 < 4; r2++) {
        const int row = orow0 + mi*16 + (l >> 4)*4 + r2;
        const float v = acc[mi][ni][r2] + bv;
        const size_t idx = (size_t)row * ldo + col;
        if constexpr (EPI == 1) ((float*)outv)[idx] = v + res[idx];
        else if constexpr (EPI == 3) ((float*)outv)[idx] = gelu_f(v) + res[idx];
        else if constexpr (EPI == 4) ((float*)outv)[idx] = v;
      }
    }
  }
}

// ---------------------------------------------------------------------------
// 128x128 single-buffered GEMM — kept for tiny head GEMMs (M=128).
// EPI: 2=bf16 gelu(bias), 5=f32 gelu(bias) bounded store [Ms,Ns]
// ---------------------------------------------------------------------------
template<int EPI>
__global__ __launch_bounds__(256) void gemm_k(
    const u16* __restrict__ A, const u16* __restrict__ Bt,
    const float* __restrict__ bias, const float* __restrict__ res,
    void* __restrict__ outv, int K, int ldo, int nbn, int Ms, int Ns)
{
  __shared__ u16 As[128*64];
  __shared__ u16 Bs[128*64];
  const int tid = threadIdx.x;
  const int l   = tid & 63;
  const int w   = tid >> 6;
  const int wm  = w >> 1, wn = w & 1;
  const int lrow = l & 15;

  const int nwg = gridDim.x;
  const int q = nwg >> 3, r = nwg & 7;
  const int xcd = blockIdx.x & 7, o = blockIdx.x >> 3;
  const int wg = (xcd < r ? xcd * (q + 1) : r * (q + 1) + (xcd - r) * q) + o;
  const int bm = wg / nbn, bn = wg % nbn;

  const int cs8 = ((tid & 7) ^ ((tid >> 3) & 7)) * 8;
  const int rb  = tid >> 3;
  const size_t abase = (size_t)bm * 128 * K;
  const size_t bbase = (size_t)bn * 128 * K;
  size_t aoff[4], boff[4];
  #pragma unroll
  for (int i = 0; i < 4; i++) {
    aoff[i] = abase + (size_t)(rb + 32 * i) * K + cs8;
    boff[i] = bbase + (size_t)(rb + 32 * i) * K + cs8;
  }

  const int colA = (l >> 4) << 4;
  const int sw   = (lrow & 7) << 4;

  f32x4 acc[4][4];
  #pragma unroll
  for (int i = 0; i < 4; i++)
    #pragma unroll
    for (int j = 0; j < 4; j++) acc[i][j] = {0.f, 0.f, 0.f, 0.f};

  const int nk = K >> 6;
  for (int kt = 0; kt < nk; ++kt) {
    const int koff = kt * 64;
    #pragma unroll
    for (int i = 0; i < 4; i++) {
      gload16(A  + aoff[i] + koff, As + tid * 8 + i * 2048);
      gload16(Bt + boff[i] + koff, Bs + tid * 8 + i * 2048);
    }
    __syncthreads();
    #pragma unroll
    for (int kk = 0; kk < 2; kk++) {
      bf16x8 af[4], bfr[4];
      #pragma unroll
      for (int mi = 0; mi < 4; mi++)
        af[mi] = *(const bf16x8*)((const char*)As +
                  ((wm*64 + mi*16 + lrow) << 7) + (((kk << 6) | colA) ^ sw));
      #pragma unroll
      for (int ni = 0; ni < 4; ni++)
        bfr[ni] = *(const bf16x8*)((const char*)Bs +
                  ((wn*64 + ni*16 + lrow) << 7) + (((kk << 6) | colA) ^ sw));
      #pragma unroll
      for (int mi = 0; mi < 4; mi++)
        #pragma unroll
        for (int ni = 0; ni < 4; ni++)
          acc[mi][ni] = __builtin_amdgcn_mfma_f32_16x16x32_bf16(af[mi], bfr[ni], acc[mi][ni], 0, 0, 0);
    }
    __syncthreads();
  }

  const int orow0 = bm*128 + wm*64;
  const int ocol0 = bn*128 + wn*64;
  #pragma unroll
  for (int mi = 0; mi < 4; mi++) {
    #pragma unroll
    for (int ni = 0; ni < 4; ni++) {
      #pragma unroll
      for (int r2 = 0; r2 < 4; r2++) {
        const int row = orow0 + mi*16 + (l >> 4)*4 + r2;
        const int col = ocol0 + ni*16 + (l & 15);
        float bv;
        if constexpr (EPI == 5) bv = (col < Ns) ? bias[col] : 0.f;
        else bv = bias[col];
        const float v = acc[mi][ni][r2] + bv;
        const size_t idx = (size_t)row * ldo + col;
        if constexpr (EPI == 2) ((u16*)outv)[idx] = f2bf(gelu_f(v));
        else if constexpr (EPI == 5) {
          if (row < Ms && col < Ns) ((float*)outv)[(size_t)row * Ns + col] = gelu_f(v);
        }
      }
    }
  }
}

// ---------------------------------------------------------------------------
__global__ void wconv_k(const float* __restrict__ W, u16* __restrict__ Wt,
                        int K, int N)
{
  __shared__ float tile[32][33];
  const int n0 = blockIdx.x * 32, k0 = blockIdx.y * 32;
  const int tx = threadIdx.x, ty = threadIdx.y;
  #pragma unroll
  for (int r = 0; r < 4; r++) {
    const int kk = k0 + ty + r*8;
    const int nn = n0 + tx;
    tile[ty + r*8][tx] = (nn < N) ? W[(size_t)kk * N + nn] : 0.f;
  }
  __syncthreads();
  #pragma unroll
  for (int r = 0; r < 4; r++) {
    const int nn = n0 + ty + r*8;
    Wt[(size_t)nn * K + k0 + tx] = f2bf(tile[tx][ty + r*8]);
  }
}

// ---------------------------------------------------------------------------
__global__ void patchify_k(const float* __restrict__ x, u16* __restrict__ hb)
{
  const int blk = blockIdx.x;
  const int b = blk / NP_, p = blk % NP_;
  const int pr = p / 24, pc = p % 24;
  const size_t row = (size_t)b * NT_ + 1 + p;
  #pragma unroll
  for (int u = 0; u < 3; u++) {
    const int j  = threadIdx.x + u * 256;
    const int c  = j >> 8, ph = (j >> 4) & 15, pw = j & 15;
    const float v = x[((size_t)(b*3 + c) * IMG_ + pr*16 + ph) * IMG_ + pc*16 + pw];
    hb[row * D_ + j] = f2bf(v);
  }
}

__global__ void posecls_k(float* __restrict__ z, const float* __restrict__ ce,
                          const float* __restrict__ pe)
{
  const int row = blockIdx.x;
  const int t = row % NT_;
  const size_t base = (size_t)row * D_;
  #pragma unroll
  for (int u = 0; u < 3; u++) {
    const int j = threadIdx.x + u * 256;
    if (t == 0) z[base + j] = ce[j] + pe[j];
    else        z[base + j] += pe[(size_t)t * D_ + j];
  }
}

// LayerNorm: one wave per row, float4 loads, f32 in -> bf16 out
__global__ void ln_k(const float* __restrict__ z, const float* __restrict__ w,
                     const float* __restrict__ b, u16* __restrict__ out)
{
  const int row = blockIdx.x * 4 + (threadIdx.x >> 6);
  const int l = threadIdx.x & 63;
  const float4* zr = (const float4*)(z + (size_t)row * D_);
  float4 xq[3];
  float s = 0.f;
  #pragma unroll
  for (int j = 0; j < 3; j++) {
    xq[j] = zr[j*64 + l];
    s += xq[j].x + xq[j].y + xq[j].z + xq[j].w;
  }
  #pragma unroll
  for (int m = 1; m < 64; m <<= 1) s += __shfl_xor(s, m, 64);
  const float mean = s * (1.0f / 768.0f);
  float ss = 0.f;
  #pragma unroll
  for (int j = 0; j < 3; j++) {
    const float dx = xq[j].x-mean, dy = xq[j].y-mean, dz = xq[j].z-mean, dw = xq[j].w-mean;
    ss += dx*dx + dy*dy + dz*dz + dw*dw;
  }
  #pragma unroll
  for (int m = 1; m < 64; m <<= 1) ss += __shfl_xor(ss, m, 64);
  const float rinv = rsqrtf(ss * (1.0f / 768.0f) + 1e-5f);
  const size_t ob = (size_t)row * D_;
  #pragma unroll
  for (int j = 0; j < 3; j++) {
    const int c = (j*64 + l) * 4;
    const float4 wv = *(const float4*)(w + c);
    const float4 bv = *(const float4*)(b + c);
    ushort4 ov;
    ov.x = f2bf((xq[j].x - mean) * rinv * wv.x + bv.x);
    ov.y = f2bf((xq[j].y - mean) * rinv * wv.y + bv.y);
    ov.z = f2bf((xq[j].z - mean) * rinv * wv.z + bv.z);
    ov.w = f2bf((xq[j].w - mean) * rinv * wv.w + bv.w);
    *(ushort4*)(out + ob + c) = ov;
  }
}

// Final LN over cls rows -> yb[128][768] bf16 (rows >= 64 zeroed)
__global__ void lncls_k(const float* __restrict__ z, const float* __restrict__ w,
                        const float* __restrict__ b, u16* __restrict__ out)
{
  const int row = blockIdx.x * 4 + (threadIdx.x >> 6);   // 0..127
  const int l = threadIdx.x & 63;
  const size_t ob = (size_t)row * D_;
  if (row >= B_) {
    #pragma unroll
    for (int j = 0; j < 12; j++) out[ob + j*64 + l] = 0;
    return;
  }
  const float* zr = z + (size_t)row * NT_ * D_;
  float xv[12];
  float s = 0.f;
  #pragma unroll
  for (int j = 0; j < 12; j++) { xv[j] = zr[j*64 + l]; s += xv[j]; }
  #pragma unroll
  for (int m = 1; m < 64; m <<= 1) s += __shfl_xor(s, m, 64);
  const float mean = s * (1.0f / 768.0f);
  float ss = 0.f;
  #pragma unroll
  for (int j = 0; j < 12; j++) { const float d = xv[j] - mean; ss += d * d; }
  #pragma unroll
  for (int m = 1; m < 64; m <<= 1) ss += __shfl_xor(ss, m, 64);
  const float rinv = rsqrtf(ss * (1.0f / 768.0f) + 1e-5f);
  #pragma unroll
  for (int j = 0; j < 12; j++) {
    const int cidx = j*64 + l;
    out[ob + cidx] = f2bf((xv[j] - mean) * rinv * w[cidx] + b[cidx]);
  }
}

// ---------------------------------------------------------------------------
// MFMA per-token head-axis attention (round-3 proven).
// ---------------------------------------------------------------------------
__global__ __launch_bounds__(256) void attn_k(const u16* __restrict__ qkv,
                                              u16* __restrict__ o)
{
  const int tok = (blockIdx.x * 256 + threadIdx.x) >> 6;
  const int l  = threadIdx.x & 63;
  const int g  = l >> 4, li = l & 15;
  const size_t rb = (size_t)tok * (3 * D_);

  f32x4 s = {0.f, 0.f, 0.f, 0.f};
  #pragma unroll
  for (int kt = 0; kt < 2; kt++) {
    const bf16x8 ka = *(const bf16x8*)(qkv + rb + D_ + li*64 + g*8 + kt*32);
    const bf16x8 qb = *(const bf16x8*)(qkv + rb +      li*64 + g*8 + kt*32);
    s = __builtin_amdgcn_mfma_f32_16x16x32_bf16(ka, qb, s, 0, 0, 0);
  }

  float sv[4];
  #pragma unroll
  for (int r2 = 0; r2 < 4; r2++) sv[r2] = s[r2] * 0.125f;
  float mx = (g < 3) ? fmaxf(fmaxf(sv[0], sv[1]), fmaxf(sv[2], sv[3])) : -1e30f;
  mx = fmaxf(mx, __shfl_xor(mx, 16, 64));
  mx = fmaxf(mx, __shfl_xor(mx, 32, 64));
  float p[4], den = 0.f;
  #pragma unroll
  for (int r2 = 0; r2 < 4; r2++) {
    p[r2] = (g < 3) ? __expf(sv[r2] - mx) : 0.f;
    den += p[r2];
  }
  den += __shfl_xor(den, 16, 64);
  den += __shfl_xor(den, 32, 64);
  const float rden = 1.0f / den;
  #pragma unroll
  for (int r2 = 0; r2 < 4; r2++) p[r2] *= rden;

  const u32 pk01 = ((u32)f2bf(p[1]) << 16) | f2bf(p[0]);
  const u32 pk23 = ((u32)f2bf(p[3]) << 16) | f2bf(p[2]);

  const int srcA = (li + (g << 5)) & 63;
  const int srcB = (srcA + 16) & 63;
  u32 b0 = (u32)__shfl((int)pk01, srcA, 64);
  u32 b1 = (u32)__shfl((int)pk23, srcA, 64);
  u32 b2 = (u32)__shfl((int)pk01, srcB, 64);
  u32 b3 = (u32)__shfl((int)pk23, srcB, 64);
  if (g >= 2) { b0 = 0; b1 = 0; b2 = 0; b3 = 0; }
  union { u32 u[4]; bf16x8 v; } pb;
  pb.u[0] = b0; pb.u[1] = b1; pb.u[2] = b2; pb.u[3] = b3;

  const size_t ob = (size_t)tok * D_;
  #pragma unroll
  for (int t = 0; t < 4; t++) {
    union { u16 a[8]; bf16x8 v; } va;
    #pragma unroll
    for (int jp = 0; jp < 8; jp++) {
      const int j = g * 8 + jp;
      va.a[jp] = (j < 12) ? qkv[rb + 2*D_ + j*64 + t*16 + li] : (u16)0;
    }
    f32x4 oac = {0.f, 0.f, 0.f, 0.f};
    oac = __builtin_amdgcn_mfma_f32_16x16x32_bf16(va.v, pb.v, oac, 0, 0, 0);
    if (li < 12) {
      ushort4 ov;
      ov.x = f2bf(oac[0]); ov.y = f2bf(oac[1]);
      ov.z = f2bf(oac[2]); ov.w = f2bf(oac[3]);
      *(ushort4*)(o + ob + li*64 + t*16 + g*4) = ov;
    }
  }
}

// ---------------------------------------------------------------------------
extern "C" void kernel_launch(void* const* d_in, const int* in_sizes, int n_in,
                              void* d_out, int out_size, void* d_ws, size_t ws_size,
                              hipStream_t stream)
{
  const float* x    = (const float*)d_in[0];
  const float* ce   = (const float*)d_in[1];
  const float* pe   = (const float*)d_in[2];
  const float* pw   = (const float*)d_in[3];
  const float* pb   = (const float*)d_in[4];
  const float* qkvw = (const float*)d_in[5];
  const float* qkvb = (const float*)d_in[6];
  const float* topw = (const float*)d_in[7];
  const float* topb = (const float*)d_in[8];
  const float* l1w  = (const float*)d_in[9];
  const float* l1b  = (const float*)d_in[10];
  const float* l2w  = (const float*)d_in[11];
  const float* l2b  = (const float*)d_in[12];
  const float* w1   = (const float*)d_in[13];
  const float* b1   = (const float*)d_in[14];
  const float* w2   = (const float*)d_in[15];
  const float* b2   = (const float*)d_in[16];
  const float* l3w  = (const float*)d_in[17];
  const float* l3b  = (const float*)d_in[18];
  const float* hw1  = (const float*)d_in[19];
  const float* hb1  = (const float*)d_in[20];
  const float* hw2  = (const float*)d_in[21];
  const float* hb2  = (const float*)d_in[22];

  char* ws = (char*)d_ws;
  constexpr size_t SZ_Z  = (size_t)MPAD2 * D_ * 4;
  constexpr size_t SZ_HB = (size_t)MPAD2 * D_ * 2;
  constexpr size_t SZ_QM = (size_t)MPAD2 * DM_ * 2;
  constexpr size_t SZ_WB = (size_t)DM_ * 1024 * 2;
  constexpr size_t SZ_YB = (size_t)128 * D_ * 2;
  float* z  = (float*)ws;
  u16*   hb = (u16*)(ws + SZ_Z);
  u16*   qm = (u16*)(ws + SZ_Z + SZ_HB);
  u16*   wb = (u16*)(ws + SZ_Z + SZ_HB + SZ_QM);
  u16*   yb = (u16*)(ws + SZ_Z + SZ_HB + SZ_QM + SZ_WB);
  u16*   t1 = (u16*)(ws + SZ_Z + SZ_HB + SZ_QM + SZ_WB + SZ_YB);

  const dim3 blk(256);
  const dim3 blk5(512);
  const dim3 wblk(32, 8);
  const int MT1 = MPAD2 / 128;  // 290
  const int MT2 = MPAD2 / 256;  // 145

  // Patch embedding
  patchify_k<<<B_ * NP_, blk, 0, stream>>>(x, hb);
  wconv_k<<<dim3(D_/32, D_/32), wblk, 0, stream>>>(pw, wb, D_, D_);
  gemm128_k<4><<<6*MT1, blk, 0, stream>>>(hb, wb, pb, nullptr, z, D_, D_, 6);
  posecls_k<<<MREAL, blk, 0, stream>>>(z, ce, pe);

  for (int i = 0; i < NL_; i++) {
    ln_k<<<MPAD2/4, blk, 0, stream>>>(z, l1w + i*D_, l1b + i*D_, hb);
    wconv_k<<<dim3(3*D_/32, D_/32), wblk, 0, stream>>>(qkvw + (size_t)i*D_*3*D_, wb, D_, 3*D_);
    gemm256_k<0><<<9*MT2, blk5, 0, stream>>>(hb, wb, qkvb + i*3*D_, qm, D_, 3*D_, 9);
    attn_k<<<MREAL/4, blk, 0, stream>>>(qm, hb);
    wconv_k<<<dim3(D_/32, D_/32), wblk, 0, stream>>>(topw + (size_t)i*D_*D_, wb, D_, D_);
    gemm128_k<1><<<6*MT1, blk, 0, stream>>>(hb, wb, topb + i*D_, z, z, D_, D_, 6);
    ln_k<<<MPAD2/4, blk, 0, stream>>>(z, l2w + i*D_, l2b + i*D_, hb);
    wconv_k<<<dim3(DM_/32, D_/32), wblk, 0, stream>>>(w1 + (size_t)i*D_*DM_, wb, D_, DM_);
    gemm256_k<2><<<12*MT2, blk5, 0, stream>>>(hb, wb, b1 + i*DM_, qm, D_, DM_, 12);
    wconv_k<<<dim3(D_/32, DM_/32), wblk, 0, stream>>>(w2 + (size_t)i*DM_*D_, wb, DM_, D_);
    gemm128_k<3><<<6*MT1, blk, 0, stream>>>(qm, wb, b2 + i*D_, z, z, DM_, D_, 6);
  }

  // Head: LN(cls) -> MLP with gelu after both linears (small M -> old kernel)
  lncls_k<<<32, blk, 0, stream>>>(z, l3w, l3b, yb);
  wconv_k<<<dim3(DM_/32, D_/32), wblk, 0, stream>>>(hw1, wb, D_, DM_);
  gemm_k<2><<<24, blk, 0, stream>>>(yb, wb, hb1, nullptr, t1, D_, DM_, 24, 0, 0);
  wconv_k<<<dim3(1024/32, DM_/32), wblk, 0, stream>>>(hw2, wb, DM_, NC_);
  gemm_k<5><<<8, blk, 0, stream>>>(t1, wb, hb2, nullptr, (float*)d_out, DM_, 1024, 8, B_, NC_);
}

// Round 8
// 11422.021 us; speedup vs baseline: 1.4643x; 1.0161x over previous
//
#include <hip/hip_runtime.h>

typedef unsigned short u16;
typedef unsigned int u32;
typedef __bf16 bf16x8 __attribute__((ext_vector_type(8)));
typedef float f32x4 __attribute__((ext_vector_type(4)));

#define D_    768
#define DM_   3072
#define NL_   12
#define NT_   577
#define NP_   576
#define B_    64
#define MREAL (B_*NT_)      /* 36928 */
#define MPAD2 37120         /* 145*256 */
#define NC_   1000
#define IMG_  384

__device__ __forceinline__ float bf2f(u16 v){
  union { unsigned u; float f; } c; c.u = ((unsigned)v) << 16; return c.f;
}
__device__ __forceinline__ u16 f2bf(float f){
  union { float f; unsigned u; } c; c.f = f;
  unsigned r = c.u + 0x7FFFu + ((c.u >> 16) & 1u);
  return (u16)(r >> 16);
}
__device__ __forceinline__ float gelu_f(float x){
  return 0.5f * x * (1.0f + erff(x * 0.70710678118654752f));
}
__device__ __forceinline__ void gload16(const void* g, void* l){
  __builtin_amdgcn_global_load_lds((const __attribute__((address_space(1))) void*)g,
                                   (__attribute__((address_space(3))) void*)l, 16, 0, 0);
}

// ---------------------------------------------------------------------------
// 8-phase 256x256 GEMM (m201-template port). BK=64, 2 K-tiles/iter, 8 waves
// (2Mx4N, wave tile 128x64). LDS: 8 slots x 16KiB = [dbuf][khalf][A,B],
// packed-row layout: logical (row R, c16) -> byte (R>>1)*128 + (R&1)*64 +
// ((c16 ^ ((R>>1)&3))<<4). Stage = linear global_load_lds dest + permuted
// per-lane SOURCE (both-sides-or-neither, rule #21). Counted vmcnt(8) at odd
// phases (ledger: 12 outstanding, retire oldest 4); last iter peeled 8/4/0.
// EPI: 0=bf16 bias, 1=f32 bias+res, 2=bf16 gelu(bias), 3=f32 gelu(bias)+res,
//      4=f32 bias
// ---------------------------------------------------------------------------
template<int EPI>
__global__ __launch_bounds__(512, 1) void gemm8p_k(
    const u16* __restrict__ A, const u16* __restrict__ Bt,
    const float* __restrict__ bias, const float* __restrict__ res,
    void* __restrict__ outv, int K, int ldo, int nbn)
{
  // slots: idx = (tile&1)*4 + khalf*2 + (0=A,1=B)
  __shared__ u16 lds[8][8192];
  const int tid = threadIdx.x;
  const int l   = tid & 63;
  const int wid = tid >> 6;
  const int wm  = wid >> 2, wn = wid & 3;
  const int lrow = l & 15;

  // bijective XCD swizzle (m204), bn-fastest
  const int nwg = gridDim.x;
  const int q = nwg >> 3, r = nwg & 7;
  const int xcd = blockIdx.x & 7, o = blockIdx.x >> 3;
  const int wg = (xcd < r ? xcd * (q + 1) : r * (q + 1) + (xcd - r) * q) + o;
  const int bm = wg / nbn, bn = wg % nbn;

  // staging: dest byte = tid*16 + j*8192 (linear). Decode -> packed (pr,half,c16s):
  // R = 2*((tid>>3)+j*64) + ((tid>>2)&1); logical c16 = (tid&3) ^ ((tid>>3)&3)
  const int Rrow = 2 * (tid >> 3) + ((tid >> 2) & 1);
  const int c16s = (tid & 3) ^ ((tid >> 3) & 3);
  const u16* aS0 = A  + (size_t)(bm*256 + Rrow) * K + c16s * 8;
  const u16* aS1 = aS0 + (size_t)128 * K;
  const u16* bS0 = Bt + (size_t)(bn*256 + Rrow) * K + c16s * 8;
  const u16* bS1 = bS0 + (size_t)128 * K;
  const int dstb = tid * 16;

  // fragment read byte offsets (within a 16KiB slot)
  int afo[8], bfo[4];
  #pragma unroll
  for (int mi = 0; mi < 8; mi++) {
    const int R = wm*128 + mi*16 + lrow;
    afo[mi] = (R >> 1)*128 + (R & 1)*64 + (((l >> 4) ^ ((R >> 1) & 3)) << 4);
  }
  #pragma unroll
  for (int ni = 0; ni < 4; ni++) {
    const int R = wn*64 + ni*16 + lrow;
    bfo[ni] = (R >> 1)*128 + (R & 1)*64 + (((l >> 4) ^ ((R >> 1) & 3)) << 4);
  }

  f32x4 acc[8][4];
  #pragma unroll
  for (int i = 0; i < 8; i++)
    #pragma unroll
    for (int j = 0; j < 4; j++) acc[i][j] = {0.f, 0.f, 0.f, 0.f};

  const int nk  = K >> 6;   // 64-wide K tiles (even: 12 or 48)
  const int nit = nk >> 1;

#define STG(t_, kk_, ab_) { \
    const u16* s0_ = ((ab_) ? bS0 : aS0) + (t_)*64 + (kk_)*32; \
    const u16* s1_ = ((ab_) ? bS1 : aS1) + (t_)*64 + (kk_)*32; \
    char* d_ = (char*)&lds[(((t_)&1)<<2) | ((kk_)<<1) | (ab_)][0]; \
    gload16(s0_, d_ + dstb); \
    gload16(s1_, d_ + dstb + 8192); }

#define PH_READS(As_, Bs_, mh_, rb_) { \
    if (rb_) { \
      _Pragma("unroll") \
      for (int n_ = 0; n_ < 4; n_++) \
        bfr[n_] = *(const bf16x8*)((const char*)&lds[Bs_][0] + bfo[n_]); \
    } \
    _Pragma("unroll") \
    for (int m_ = 0; m_ < 4; m_++) \
      af[m_] = *(const bf16x8*)((const char*)&lds[As_][0] + afo[(mh_)*4 + m_]); }

#define PH_MFMA(mh_) { \
    __builtin_amdgcn_s_setprio(1); \
    _Pragma("unroll") \
    for (int m_ = 0; m_ < 4; m_++) \
      _Pragma("unroll") \
      for (int n_ = 0; n_ < 4; n_++) \
        acc[(mh_)*4 + m_][n_] = __builtin_amdgcn_mfma_f32_16x16x32_bf16(af[m_], bfr[n_], acc[(mh_)*4 + m_][n_], 0, 0, 0); \
    __builtin_amdgcn_s_setprio(0); }

#define BARX __builtin_amdgcn_s_barrier()
#define VMW(n_) asm volatile("s_waitcnt vmcnt(" #n_ ")" ::: "memory")

  // prologue: stage t0k0, t0k1, t1k0 (12 loads/wave); wait t0k0 (oldest 4)
  STG(0,0,0); STG(0,0,1); STG(0,1,0); STG(0,1,1); STG(1,0,0); STG(1,0,1);
  VMW(8);
  BARX;

  for (int i = 0; i < nit; ++i) {
    const int t1 = 2*i + 1, t2 = 2*i + 2, t3 = 2*i + 3;
    const bool lastI = (i == nit - 1);
    bf16x8 af[4], bfr[4];

    // p0: (t0,k0,m0)  stage t1k1.A
    PH_READS(0, 1, 0, 1); STG(t1,1,0);
    BARX; PH_MFMA(0); BARX;
    // p1: (t0,k0,m1)  stage t1k1.B ; W: protect p2 (t0k1, prev p4/p5)
    PH_READS(0, 1, 1, 0); STG(t1,1,1);
    BARX; PH_MFMA(1);
    VMW(8); BARX;
    // p2: (t0,k1,m0)  stage t2k0.A
    PH_READS(2, 3, 0, 1); if (!lastI) { STG(t2,0,0); }
    BARX; PH_MFMA(0); BARX;
    // p3: (t0,k1,m1)  stage t2k0.B ; W: protect p4 (t1k0, prev p6/p7)
    PH_READS(2, 3, 1, 0); if (!lastI) { STG(t2,0,1); }
    BARX; PH_MFMA(1);
    if (lastI) { VMW(4); } else { VMW(8); }
    BARX;
    // p4: (t1,k0,m0)  stage t2k1.A
    PH_READS(4, 5, 0, 1); if (!lastI) { STG(t2,1,0); }
    BARX; PH_MFMA(0); BARX;
    // p5: (t1,k0,m1)  stage t2k1.B ; W: protect p6 (t1k1, this p0/p1)
    PH_READS(4, 5, 1, 0); if (!lastI) { STG(t2,1,1); }
    BARX; PH_MFMA(1);
    if (lastI) { VMW(0); } else { VMW(8); }
    BARX;
    // p6: (t1,k1,m0)  stage t3k0.A
    PH_READS(6, 7, 0, 1); if (!lastI) { STG(t3,0,0); }
    BARX; PH_MFMA(0); BARX;
    // p7: (t1,k1,m1)  stage t3k0.B ; W: protect next p0 (t2k0, p2/p3)
    PH_READS(6, 7, 1, 0); if (!lastI) { STG(t3,0,1); }
    BARX; PH_MFMA(1);
    if (!lastI) { VMW(8); }
    BARX;
  }

  const int orow0 = bm*256 + wm*128;
  const int ocol0 = bn*256 + wn*64;
  #pragma unroll
  for (int mi = 0; mi < 8; mi++) {
    #pragma unroll
    for (int ni = 0; ni < 4; ni++) {
      const int col = ocol0 + ni*16 + (l & 15);
      const float bv = bias[col];
      #pragma unroll
      for (int r2 = 0; r2 < 4; r2++) {
        const int row = orow0 + mi*16 + (l >> 4)*4 + r2;
        const float v = acc[mi][ni][r2] + bv;
        const size_t idx = (size_t)row * ldo + col;
        if constexpr (EPI == 0) ((u16*)outv)[idx] = f2bf(v);
        else if constexpr (EPI == 1) ((float*)outv)[idx] = v + res[idx];
        else if constexpr (EPI == 2) ((u16*)outv)[idx] = f2bf(gelu_f(v));
        else if constexpr (EPI == 3) ((float*)outv)[idx] = gelu_f(v) + res[idx];
        else if constexpr (EPI == 4) ((float*)outv)[idx] = v;
      }
    }
  }
#undef STG
#undef PH_READS
#undef PH_MFMA
#undef BARX
#undef VMW
}

// ---------------------------------------------------------------------------
// 128x128 single-buffered GEMM — kept for tiny head GEMMs (M=128).
// EPI: 2=bf16 gelu(bias), 5=f32 gelu(bias) bounded store [Ms,Ns]
// ---------------------------------------------------------------------------
template<int EPI>
__global__ __launch_bounds__(256) void gemm_k(
    const u16* __restrict__ A, const u16* __restrict__ Bt,
    const float* __restrict__ bias, const float* __restrict__ res,
    void* __restrict__ outv, int K, int ldo, int nbn, int Ms, int Ns)
{
  __shared__ u16 As[128*64];
  __shared__ u16 Bs[128*64];
  const int tid = threadIdx.x;
  const int l   = tid & 63;
  const int w   = tid >> 6;
  const int wm  = w >> 1, wn = w & 1;
  const int lrow = l & 15;

  const int nwg = gridDim.x;
  const int q = nwg >> 3, r = nwg & 7;
  const int xcd = blockIdx.x & 7, o = blockIdx.x >> 3;
  const int wg = (xcd < r ? xcd * (q + 1) : r * (q + 1) + (xcd - r) * q) + o;
  const int bm = wg / nbn, bn = wg % nbn;

  const int cs8 = ((tid & 7) ^ ((tid >> 3) & 7)) * 8;
  const int rb  = tid >> 3;
  const size_t abase = (size_t)bm * 128 * K;
  const size_t bbase = (size_t)bn * 128 * K;
  size_t aoff[4], boff[4];
  #pragma unroll
  for (int i = 0; i < 4; i++) {
    aoff[i] = abase + (size_t)(rb + 32 * i) * K + cs8;
    boff[i] = bbase + (size_t)(rb + 32 * i) * K + cs8;
  }

  const int colA = (l >> 4) << 4;
  const int sw   = (lrow & 7) << 4;

  f32x4 acc[4][4];
  #pragma unroll
  for (int i = 0; i < 4; i++)
    #pragma unroll
    for (int j = 0; j < 4; j++) acc[i][j] = {0.f, 0.f, 0.f, 0.f};

  const int nk = K >> 6;
  for (int kt = 0; kt < nk; ++kt) {
    const int koff = kt * 64;
    #pragma unroll
    for (int i = 0; i < 4; i++) {
      gload16(A  + aoff[i] + koff, As + tid * 8 + i * 2048);
      gload16(Bt + boff[i] + koff, Bs + tid * 8 + i * 2048);
    }
    __syncthreads();
    #pragma unroll
    for (int kk = 0; kk < 2; kk++) {
      bf16x8 af[4], bfr[4];
      #pragma unroll
      for (int mi = 0; mi < 4; mi++)
        af[mi] = *(const bf16x8*)((const char*)As +
                  ((wm*64 + mi*16 + lrow) << 7) + (((kk << 6) | colA) ^ sw));
      #pragma unroll
      for (int ni = 0; ni < 4; ni++)
        bfr[ni] = *(const bf16x8*)((const char*)Bs +
                  ((wn*64 + ni*16 + lrow) << 7) + (((kk << 6) | colA) ^ sw));
      #pragma unroll
      for (int mi = 0; mi < 4; mi++)
        #pragma unroll
        for (int ni = 0; ni < 4; ni++)
          acc[mi][ni] = __builtin_amdgcn_mfma_f32_16x16x32_bf16(af[mi], bfr[ni], acc[mi][ni], 0, 0, 0);
    }
    __syncthreads();
  }

  const int orow0 = bm*128 + wm*64;
  const int ocol0 = bn*128 + wn*64;
  #pragma unroll
  for (int mi = 0; mi < 4; mi++) {
    #pragma unroll
    for (int ni = 0; ni < 4; ni++) {
      #pragma unroll
      for (int r2 = 0; r2 < 4; r2++) {
        const int row = orow0 + mi*16 + (l >> 4)*4 + r2;
        const int col = ocol0 + ni*16 + (l & 15);
        float bv;
        if constexpr (EPI == 5) bv = (col < Ns) ? bias[col] : 0.f;
        else bv = bias[col];
        const float v = acc[mi][ni][r2] + bv;
        const size_t idx = (size_t)row * ldo + col;
        if constexpr (EPI == 2) ((u16*)outv)[idx] = f2bf(gelu_f(v));
        else if constexpr (EPI == 5) {
          if (row < Ms && col < Ns) ((float*)outv)[(size_t)row * Ns + col] = gelu_f(v);
        }
      }
    }
  }
}

// ---------------------------------------------------------------------------
__global__ void wconv_k(const float* __restrict__ W, u16* __restrict__ Wt,
                        int K, int N)
{
  __shared__ float tile[32][33];
  const int n0 = blockIdx.x * 32, k0 = blockIdx.y * 32;
  const int tx = threadIdx.x, ty = threadIdx.y;
  #pragma unroll
  for (int r = 0; r < 4; r++) {
    const int kk = k0 + ty + r*8;
    const int nn = n0 + tx;
    tile[ty + r*8][tx] = (nn < N) ? W[(size_t)kk * N + nn] : 0.f;
  }
  __syncthreads();
  #pragma unroll
  for (int r = 0; r < 4; r++) {
    const int nn = n0 + ty + r*8;
    Wt[(size_t)nn * K + k0 + tx] = f2bf(tile[tx][ty + r*8]);
  }
}

// ---------------------------------------------------------------------------
__global__ void patchify_k(const float* __restrict__ x, u16* __restrict__ hb)
{
  const int blk = blockIdx.x;
  const int b = blk / NP_, p = blk % NP_;
  const int pr = p / 24, pc = p % 24;
  const size_t row = (size_t)b * NT_ + 1 + p;
  #pragma unroll
  for (int u = 0; u < 3; u++) {
    const int j  = threadIdx.x + u * 256;
    const int c  = j >> 8, ph = (j >> 4) & 15, pw = j & 15;
    const float v = x[((size_t)(b*3 + c) * IMG_ + pr*16 + ph) * IMG_ + pc*16 + pw];
    hb[row * D_ + j] = f2bf(v);
  }
}

__global__ void posecls_k(float* __restrict__ z, const float* __restrict__ ce,
                          const float* __restrict__ pe)
{
  const int row = blockIdx.x;
  const int t = row % NT_;
  const size_t base = (size_t)row * D_;
  #pragma unroll
  for (int u = 0; u < 3; u++) {
    const int j = threadIdx.x + u * 256;
    if (t == 0) z[base + j] = ce[j] + pe[j];
    else        z[base + j] += pe[(size_t)t * D_ + j];
  }
}

// LayerNorm: one wave per row, float4 loads, f32 in -> bf16 out
__global__ void ln_k(const float* __restrict__ z, const float* __restrict__ w,
                     const float* __restrict__ b, u16* __restrict__ out)
{
  const int row = blockIdx.x * 4 + (threadIdx.x >> 6);
  const int l = threadIdx.x & 63;
  const float4* zr = (const float4*)(z + (size_t)row * D_);
  float4 xq[3];
  float s = 0.f;
  #pragma unroll
  for (int j = 0; j < 3; j++) {
    xq[j] = zr[j*64 + l];
    s += xq[j].x + xq[j].y + xq[j].z + xq[j].w;
  }
  #pragma unroll
  for (int m = 1; m < 64; m <<= 1) s += __shfl_xor(s, m, 64);
  const float mean = s * (1.0f / 768.0f);
  float ss = 0.f;
  #pragma unroll
  for (int j = 0; j < 3; j++) {
    const float dx = xq[j].x-mean, dy = xq[j].y-mean, dz = xq[j].z-mean, dw = xq[j].w-mean;
    ss += dx*dx + dy*dy + dz*dz + dw*dw;
  }
  #pragma unroll
  for (int m = 1; m < 64; m <<= 1) ss += __shfl_xor(ss, m, 64);
  const float rinv = rsqrtf(ss * (1.0f / 768.0f) + 1e-5f);
  const size_t ob = (size_t)row * D_;
  #pragma unroll
  for (int j = 0; j < 3; j++) {
    const int c = (j*64 + l) * 4;
    const float4 wv = *(const float4*)(w + c);
    const float4 bv = *(const float4*)(b + c);
    ushort4 ov;
    ov.x = f2bf((xq[j].x - mean) * rinv * wv.x + bv.x);
    ov.y = f2bf((xq[j].y - mean) * rinv * wv.y + bv.y);
    ov.z = f2bf((xq[j].z - mean) * rinv * wv.z + bv.z);
    ov.w = f2bf((xq[j].w - mean) * rinv * wv.w + bv.w);
    *(ushort4*)(out + ob + c) = ov;
  }
}

// Final LN over cls rows -> yb[128][768] bf16 (rows >= 64 zeroed)
__global__ void lncls_k(const float* __restrict__ z, const float* __restrict__ w,
                        const float* __restrict__ b, u16* __restrict__ out)
{
  const int row = blockIdx.x * 4 + (threadIdx.x >> 6);   // 0..127
  const int l = threadIdx.x & 63;
  const size_t ob = (size_t)row * D_;
  if (row >= B_) {
    #pragma unroll
    for (int j = 0; j < 12; j++) out[ob + j*64 + l] = 0;
    return;
  }
  const float* zr = z + (size_t)row * NT_ * D_;
  float xv[12];
  float s = 0.f;
  #pragma unroll
  for (int j = 0; j < 12; j++) { xv[j] = zr[j*64 + l]; s += xv[j]; }
  #pragma unroll
  for (int m = 1; m < 64; m <<= 1) s += __shfl_xor(s, m, 64);
  const float mean = s * (1.0f / 768.0f);
  float ss = 0.f;
  #pragma unroll
  for (int j = 0; j < 12; j++) { const float d = xv[j] - mean; ss += d * d; }
  #pragma unroll
  for (int m = 1; m < 64; m <<= 1) ss += __shfl_xor(ss, m, 64);
  const float rinv = rsqrtf(ss * (1.0f / 768.0f) + 1e-5f);
  #pragma unroll
  for (int j = 0; j < 12; j++) {
    const int cidx = j*64 + l;
    out[ob + cidx] = f2bf((xv[j] - mean) * rinv * w[cidx] + b[cidx]);
  }
}

// ---------------------------------------------------------------------------
// MFMA per-token head-axis attention (round-3 proven).
// ---------------------------------------------------------------------------
__global__ __launch_bounds__(256) void attn_k(const u16* __restrict__ qkv,
                                              u16* __restrict__ o)
{
  const int tok = (blockIdx.x * 256 + threadIdx.x) >> 6;
  const int l  = threadIdx.x & 63;
  const int g  = l >> 4, li = l & 15;
  const size_t rb = (size_t)tok * (3 * D_);

  f32x4 s = {0.f, 0.f, 0.f, 0.f};
  #pragma unroll
  for (int kt = 0; kt < 2; kt++) {
    const bf16x8 ka = *(const bf16x8*)(qkv + rb + D_ + li*64 + g*8 + kt*32);
    const bf16x8 qb = *(const bf16x8*)(qkv + rb +      li*64 + g*8 + kt*32);
    s = __builtin_amdgcn_mfma_f32_16x16x32_bf16(ka, qb, s, 0, 0, 0);
  }

  float sv[4];
  #pragma unroll
  for (int r2 = 0; r2 < 4; r2++) sv[r2] = s[r2] * 0.125f;
  float mx = (g < 3) ? fmaxf(fmaxf(sv[0], sv[1]), fmaxf(sv[2], sv[3])) : -1e30f;
  mx = fmaxf(mx, __shfl_xor(mx, 16, 64));
  mx = fmaxf(mx, __shfl_xor(mx, 32, 64));
  float p[4], den = 0.f;
  #pragma unroll
  for (int r2 = 0; r2 < 4; r2++) {
    p[r2] = (g < 3) ? __expf(sv[r2] - mx) : 0.f;
    den += p[r2];
  }
  den += __shfl_xor(den, 16, 64);
  den += __shfl_xor(den, 32, 64);
  const float rden = 1.0f / den;
  #pragma unroll
  for (int r2 = 0; r2 < 4; r2++) p[r2] *= rden;

  const u32 pk01 = ((u32)f2bf(p[1]) << 16) | f2bf(p[0]);
  const u32 pk23 = ((u32)f2bf(p[3]) << 16) | f2bf(p[2]);

  const int srcA = (li + (g << 5)) & 63;
  const int srcB = (srcA + 16) & 63;
  u32 b0 = (u32)__shfl((int)pk01, srcA, 64);
  u32 b1 = (u32)__shfl((int)pk23, srcA, 64);
  u32 b2 = (u32)__shfl((int)pk01, srcB, 64);
  u32 b3 = (u32)__shfl((int)pk23, srcB, 64);
  if (g >= 2) { b0 = 0; b1 = 0; b2 = 0; b3 = 0; }
  union { u32 u[4]; bf16x8 v; } pb;
  pb.u[0] = b0; pb.u[1] = b1; pb.u[2] = b2; pb.u[3] = b3;

  const size_t ob = (size_t)tok * D_;
  #pragma unroll
  for (int t = 0; t < 4; t++) {
    union { u16 a[8]; bf16x8 v; } va;
    #pragma unroll
    for (int jp = 0; jp < 8; jp++) {
      const int j = g * 8 + jp;
      va.a[jp] = (j < 12) ? qkv[rb + 2*D_ + j*64 + t*16 + li] : (u16)0;
    }
    f32x4 oac = {0.f, 0.f, 0.f, 0.f};
    oac = __builtin_amdgcn_mfma_f32_16x16x32_bf16(va.v, pb.v, oac, 0, 0, 0);
    if (li < 12) {
      ushort4 ov;
      ov.x = f2bf(oac[0]); ov.y = f2bf(oac[1]);
      ov.z = f2bf(oac[2]); ov.w = f2bf(oac[3]);
      *(ushort4*)(o + ob + li*64 + t*16 + g*4) = ov;
    }
  }
}

// ---------------------------------------------------------------------------
extern "C" void kernel_launch(void* const* d_in, const int* in_sizes, int n_in,
                              void* d_out, int out_size, void* d_ws, size_t ws_size,
                              hipStream_t stream)
{
  const float* x    = (const float*)d_in[0];
  const float* ce   = (const float*)d_in[1];
  const float* pe   = (const float*)d_in[2];
  const float* pw   = (const float*)d_in[3];
  const float* pb   = (const float*)d_in[4];
  const float* qkvw = (const float*)d_in[5];
  const float* qkvb = (const float*)d_in[6];
  const float* topw = (const float*)d_in[7];
  const float* topb = (const float*)d_in[8];
  const float* l1w  = (const float*)d_in[9];
  const float* l1b  = (const float*)d_in[10];
  const float* l2w  = (const float*)d_in[11];
  const float* l2b  = (const float*)d_in[12];
  const float* w1   = (const float*)d_in[13];
  const float* b1   = (const float*)d_in[14];
  const float* w2   = (const float*)d_in[15];
  const float* b2   = (const float*)d_in[16];
  const float* l3w  = (const float*)d_in[17];
  const float* l3b  = (const float*)d_in[18];
  const float* hw1  = (const float*)d_in[19];
  const float* hb1  = (const float*)d_in[20];
  const float* hw2  = (const float*)d_in[21];
  const float* hb2  = (const float*)d_in[22];

  char* ws = (char*)d_ws;
  constexpr size_t SZ_Z  = (size_t)MPAD2 * D_ * 4;
  constexpr size_t SZ_HB = (size_t)MPAD2 * D_ * 2;
  constexpr size_t SZ_QM = (size_t)MPAD2 * DM_ * 2;
  constexpr size_t SZ_WB = (size_t)DM_ * 1024 * 2;
  constexpr size_t SZ_YB = (size_t)128 * D_ * 2;
  float* z  = (float*)ws;
  u16*   hb = (u16*)(ws + SZ_Z);
  u16*   qm = (u16*)(ws + SZ_Z + SZ_HB);
  u16*   wb = (u16*)(ws + SZ_Z + SZ_HB + SZ_QM);
  u16*   yb = (u16*)(ws + SZ_Z + SZ_HB + SZ_QM + SZ_WB);
  u16*   t1 = (u16*)(ws + SZ_Z + SZ_HB + SZ_QM + SZ_WB + SZ_YB);

  const dim3 blk(256);
  const dim3 blk5(512);
  const dim3 wblk(32, 8);
  const int MT2 = MPAD2 / 256;  // 145

  // Patch embedding
  patchify_k<<<B_ * NP_, blk, 0, stream>>>(x, hb);
  wconv_k<<<dim3(D_/32, D_/32), wblk, 0, stream>>>(pw, wb, D_, D_);
  gemm8p_k<4><<<3*MT2, blk5, 0, stream>>>(hb, wb, pb, nullptr, z, D_, D_, 3);
  posecls_k<<<MREAL, blk, 0, stream>>>(z, ce, pe);

  for (int i = 0; i < NL_; i++) {
    ln_k<<<MPAD2/4, blk, 0, stream>>>(z, l1w + i*D_, l1b + i*D_, hb);
    wconv_k<<<dim3(3*D_/32, D_/32), wblk, 0, stream>>>(qkvw + (size_t)i*D_*3*D_, wb, D_, 3*D_);
    gemm8p_k<0><<<9*MT2, blk5, 0, stream>>>(hb, wb, qkvb + i*3*D_, nullptr, qm, D_, 3*D_, 9);
    attn_k<<<MREAL/4, blk, 0, stream>>>(qm, hb);
    wconv_k<<<dim3(D_/32, D_/32), wblk, 0, stream>>>(topw + (size_t)i*D_*D_, wb, D_, D_);
    gemm8p_k<1><<<3*MT2, blk5, 0, stream>>>(hb, wb, topb + i*D_, z, z, D_, D_, 3);
    ln_k<<<MPAD2/4, blk, 0, stream>>>(z, l2w + i*D_, l2b + i*D_, hb);
    wconv_k<<<dim3(DM_/32, D_/32), wblk, 0, stream>>>(w1 + (size_t)i*D_*DM_, wb, D_, DM_);
    gemm8p_k<2><<<12*MT2, blk5, 0, stream>>>(hb, wb, b1 + i*DM_, nullptr, qm, D_, DM_, 12);
    wconv_k<<<dim3(D_/32, DM_/32), wblk, 0, stream>>>(w2 + (size_t)i*DM_*D_, wb, DM_, D_);
    gemm8p_k<3><<<3*MT2, blk5, 0, stream>>>(qm, wb, b2 + i*D_, z, z, DM_, D_, 3);
  }

  // Head: LN(cls) -> MLP with gelu after both linears (small M -> old kernel)
  lncls_k<<<32, blk, 0, stream>>>(z, l3w, l3b, yb);
  wconv_k<<<dim3(DM_/32, D_/32), wblk, 0, stream>>>(hw1, wb, D_, DM_);
  gemm_k<2><<<24, blk, 0, stream>>>(yb, wb, hb1, nullptr, t1, D_, DM_, 24, 0, 0);
  wconv_k<<<dim3(1024/32, DM_/32), wblk, 0, stream>>>(hw2, wb, DM_, NC_);
  gemm_k<5><<<8, blk, 0, stream>>>(t1, wb, hb2, nullptr, (float*)d_out, DM_, 1024, 8, B_, NC_);
}